// Round 1
// 299.827 us; speedup vs baseline: 1.0769x; 1.0769x over previous
//
#include <hip/hip_runtime.h>
#include <math.h>

constexpr int M   = 64;       // rows of phi / Y
constexpr int NR  = 256;      // rows of X
constexpr int KK  = NR + M;   // 320: stacked K dim  [W | Z] · [X ; Y]
constexpr int NC  = 131072;   // columns
constexpr int BN  = 64;       // columns per block
constexpr float THR = 0.1f;

typedef __bf16 bf16x8 __attribute__((ext_vector_type(8)));
typedef float  f32x4  __attribute__((ext_vector_type(4)));

static __device__ __forceinline__ unsigned short f2bf(float f) {
    unsigned int u = __float_as_uint(f);
    u += 0x7FFFu + ((u >> 16) & 1u);        // round-to-nearest-even
    return (unsigned short)(u >> 16);
}

// A stored fragment-linear: chunk ((wave*10 + kb)*4 + mt) of 512 bf16 (1 KiB);
// element (lane*8 + j) within chunk, lane = quad*16 + nlo.
// Fragment element (lane, j) <-> A(i = wave*64 + mt*16 + nlo, kk = kb*32 + quad*8 + j)
static __device__ __forceinline__ int a_off(int i, int kk) {
    const int wave = i >> 6, mt = (i >> 4) & 3, nlo = i & 15;
    const int kb = kk >> 5, quad = (kk >> 3) & 3, j = kk & 7;
    return (((wave * 10 + kb) * 4 + mt) << 9) + ((quad * 16 + nlo) << 3) + j;
}

__global__ __launch_bounds__(256)
void k_copy_phi(const float* __restrict__ phi, float* __restrict__ out)
{
    int i = blockIdx.x * 256 + threadIdx.x;
    out[i] = phi[i];
}

// Build A = [ I - s*phi^T*phi  |  s*phi^T ]  (256 x 320, bf16) in ws,
// stored in MFMA-fragment-linear order (a_off). Block i computes row i.
__global__ __launch_bounds__(256)
void k_prep(const float* __restrict__ phi, const float* __restrict__ step,
            unsigned short* __restrict__ A)
{
    __shared__ float ph[M * NR];            // 64 KiB, phi row-major 64x256
    const int i = blockIdx.x, j = threadIdx.x;
    for (int t = j; t < M * NR; t += 256) ph[t] = phi[t];
    __syncthreads();
    const float s = step[0];
    float d = 0.f;
    #pragma unroll
    for (int m = 0; m < M; ++m)
        d = fmaf(ph[m * NR + i], ph[m * NR + j], d);
    float w = ((i == j) ? 1.f : 0.f) - s * d;
    A[a_off(i, j)] = f2bf(w);
    if (j < M) A[a_off(i, NR + j)] = f2bf(s * ph[j * NR + i]);
}

// U = A[256x320] * [X;Y][320xN], threshold, copy for cols >= k.
// Block: 256 thr = 4 waves; BN=64 cols; wave w owns U rows 64w..64w+63.
// LDS B: bf16, zero-pad, XOR-swizzled:
//   byte(kb,n,kl) = kb*4096 + n*64 + kl*2, then ^ ((n>>1)&7)<<4
//   -> ds_read_b128 fragment reads are bank-uniform (conflict-free),
//      staging ds_write_b32 is 4-way. Total 40960 B -> 4 blocks/CU.
__global__ __launch_bounds__(256, 4)
void k_gemm(const unsigned short* __restrict__ A,
            const float* __restrict__ X,
            const float* __restrict__ Y,
            const int*   __restrict__ idxp,
            float* __restrict__ outX)
{
    const int k   = idxp[0] + 1;
    const int n0  = blockIdx.x * BN;
    const int tid = threadIdx.x;

    if (n0 >= k) {                           // pure-copy fast path
        const int c4 = tid & 15, rg = tid >> 4;
        #pragma unroll
        for (int r = rg; r < NR; r += 16) {
            const float4* src = (const float4*)(X + (size_t)r * NC + n0);
            float4*       dst = (float4*)(outX + (size_t)r * NC + n0);
            dst[c4] = src[c4];
        }
        return;
    }

    __shared__ unsigned int Bu32[10 * 4096 / 4];   // 40960 B

    const int c4 = tid & 15, rg = tid >> 4;
    const int lane = tid & 63, wave = tid >> 6;
    const int quad = lane >> 4, nlo = lane & 15;

    // ---- burst-load the whole [X;Y] tile into registers (20 float4 in flight) ----
    f32x4 v0[10], v1[10];
    #pragma unroll
    for (int it = 0; it < 10; ++it) {
        const int r0 = 32 * it + 2 * rg;     // even row; pair never crosses X/Y seam
        const float *s0, *s1;
        if (r0 < NR) { s0 = X + (size_t)r0 * NC;        s1 = X + (size_t)(r0 + 1) * NC; }
        else         { s0 = Y + (size_t)(r0 - NR) * NC; s1 = Y + (size_t)(r0 + 1 - NR) * NC; }
        v0[it] = *(const f32x4*)(s0 + n0 + 4 * c4);
        v1[it] = *(const f32x4*)(s1 + n0 + 4 * c4);
    }

    // ---- prefetch A fragments for kb=0 (coalesced 1KB/wave chunks, L2-hot) ----
    const unsigned short* Abase = A + ((wave * 40) << 9) + (lane << 3);
    bf16x8 a_cur[4], a_nxt[4];
    #pragma unroll
    for (int mt = 0; mt < 4; ++mt)
        a_cur[mt] = *(const bf16x8*)(Abase + (mt << 9));

    // ---- convert + write swizzled LDS ----
    #pragma unroll
    for (int it = 0; it < 10; ++it) {
        const int kl2 = 4 * rg;              // kl*2 bytes, kl = 2*rg
        #pragma unroll
        for (int c = 0; c < 4; ++c) {
            const int n = 4 * c4 + c;
            const int byteoff = (it * 4096 + n * 64 + kl2) ^ ((n & 14) << 3);
            Bu32[byteoff >> 2] =
                (unsigned int)f2bf(v0[it][c]) | ((unsigned int)f2bf(v1[it][c]) << 16);
        }
    }
    __syncthreads();

    f32x4 acc[4][4];
    #pragma unroll
    for (int mt = 0; mt < 4; ++mt)
        #pragma unroll
        for (int nt = 0; nt < 4; ++nt)
            acc[mt][nt] = (f32x4){0.f, 0.f, 0.f, 0.f};

    // swz for reads: n = nlo + nt*16 -> ((n>>1)&7)<<4 == ((nlo>>1)&7)<<4 (nt-independent)
    const char* Bbase = (const char*)Bu32 +
                        (((unsigned)(nlo * 64 + quad * 16)) ^ ((nlo & 14) << 3));

    #pragma unroll
    for (int kb = 0; kb < 10; ++kb) {
        if (kb < 9) {                        // 1-deep A prefetch across kb
            #pragma unroll
            for (int mt = 0; mt < 4; ++mt)
                a_nxt[mt] = *(const bf16x8*)(Abase + (((kb + 1) * 4 + mt) << 9));
        }
        bf16x8 bfr[4];
        #pragma unroll
        for (int nt = 0; nt < 4; ++nt)
            bfr[nt] = *(const bf16x8*)(Bbase + kb * 4096 + nt * 1024);
        #pragma unroll
        for (int mt = 0; mt < 4; ++mt)
            #pragma unroll
            for (int nt = 0; nt < 4; ++nt)
                acc[mt][nt] = __builtin_amdgcn_mfma_f32_16x16x32_bf16(
                    a_cur[mt], bfr[nt], acc[mt][nt], 0, 0, 0);
        #pragma unroll
        for (int mt = 0; mt < 4; ++mt) a_cur[mt] = a_nxt[mt];
    }

    // ---- epilogue: threshold + boundary copy + store ----
    const int mbase = wave * 64;
    const bool boundary = (n0 + BN > k);
    #pragma unroll
    for (int mt = 0; mt < 4; ++mt) {
        #pragma unroll
        for (int nt = 0; nt < 4; ++nt) {
            const int col = n0 + nt * 16 + nlo;
            #pragma unroll
            for (int reg = 0; reg < 4; ++reg) {
                const int row = mbase + mt * 16 + quad * 4 + reg;
                float v = acc[mt][nt][reg];
                v = (fabsf(v) > THR) ? v : 0.f;
                if (boundary && col >= k) v = X[(size_t)row * NC + col];
                outX[(size_t)row * NC + col] = v;
            }
        }
    }
}

extern "C" void kernel_launch(void* const* d_in, const int* in_sizes, int n_in,
                              void* d_out, int out_size, void* d_ws, size_t ws_size,
                              hipStream_t stream)
{
    const float* phi  = (const float*)d_in[0];
    const float* X    = (const float*)d_in[1];
    const float* Y    = (const float*)d_in[2];
    const float* step = (const float*)d_in[3];
    const int*   idx  = (const int*)d_in[4];
    float* out = (float*)d_out;
    unsigned short* A = (unsigned short*)d_ws;   // 256*320*2 = 160 KiB, fragment-linear

    k_copy_phi<<<(M * NR) / 256, 256, 0, stream>>>(phi, out);
    k_prep<<<NR, 256, 0, stream>>>(phi, step, A);
    k_gemm<<<NC / BN, 256, 0, stream>>>(A, X, Y, idx, out + M * NR);
}